// Round 13
// baseline (473.839 us; speedup 1.0000x reference)
//
#include <hip/hip_runtime.h>
#include <stdint.h>

// Depthwise causal conv via MFMA Toeplitz, f16 compute, f32 LDS staging.
//   y[p,q] = sum_{r,s} w[r,s] * xm[p+r-5, q+s-5], xm/out causally masked.
// A = Toeplitz weights (m = local q), B = x tile (n = local p):
//   A[m,k] = w[r, k-m-3] for k-m-3 in [0,10] else 0
//   B[k,n] = x[psub + n + r - 5, q0 + 16*qt - 8 + k]
// Block = 64q x 64p as TWO 32-row sub-tiles, double-buffered:
//   stage A | sync | issue stage B (global_load_lds: ZERO register carry,
//   spill-proof) | compute A | sync | compute B.
// x staged as f32 (enables gll DMA); f32->f16 via v_cvt_pkrtz at fragment
// read, hidden under MFMA. N=2, C=16, H=W=2048.

#define HDIM 2048
#define WDIM 2048
#define CH   16

#define PITCHF 80           // f32 per LDS row (320B): linear rows -> gll-legal
#define TROWS  37           // 32 + 5 halo rows
#define NSL    (TROWS * 20) // 740 16B granules per sub-tile

typedef float    f32x4 __attribute__((ext_vector_type(4)));
typedef __fp16   h16x2 __attribute__((ext_vector_type(2)));
typedef __fp16   h16x8 __attribute__((ext_vector_type(8)));
typedef _Float16 f16x8 __attribute__((ext_vector_type(8)));

typedef const __attribute__((address_space(1))) uint32_t* gptr_t;
typedef __attribute__((address_space(3))) uint32_t* lptr_t;

static __device__ __forceinline__ f16x8 pack8(f32x4 a, f32x4 b) {
  union { h16x2 h[4]; f16x8 v; } u;
  u.h[0] = __builtin_amdgcn_cvt_pkrtz(a[0], a[1]);
  u.h[1] = __builtin_amdgcn_cvt_pkrtz(a[2], a[3]);
  u.h[2] = __builtin_amdgcn_cvt_pkrtz(b[0], b[1]);
  u.h[3] = __builtin_amdgcn_cvt_pkrtz(b[2], b[3]);
  return u.v;
}

static __device__ __forceinline__ void stage_tile(
    const float* __restrict__ xp, int p0, int q0, int bx, int tid,
    float* __restrict__ buf) {
  // pure: staged rows [p0-5,p0+32), cols [q0-8,q0+72) in-bounds AND causal.
  const bool pure = (bx >= 1) && (bx <= 30) && (p0 >= q0 + 76);
  if (pure) {
    // Async DMA to LDS; slot->LDS mapping is linear (wave-uniform base +
    // lane*16, prefix-contiguous guard) -> no VGPR roundtrip, no spill risk.
#pragma unroll
    for (int j = 0; j < 3; ++j) {
      int slot = j * 256 + tid;
      if (slot < NSL) {
        int row = slot / 20;
        int c4 = slot - row * 20;
        const float* ga =
            xp + (size_t)(p0 - 5 + row) * WDIM + (q0 - 8 + 4 * c4);
        __builtin_amdgcn_global_load_lds((gptr_t)ga, (lptr_t)(buf + slot * 4),
                                         16, 0, 0);
      }
    }
  } else {
#pragma unroll
    for (int j = 0; j < 3; ++j) {
      int slot = j * 256 + tid;
      if (slot < NSL) {
        int row = slot / 20;
        int c4 = slot - row * 20;
        int ih = p0 - 5 + row;
        int cb = q0 - 8 + 4 * c4;
        float4 v = make_float4(0.f, 0.f, 0.f, 0.f);
        if (ih >= 0) {  // ih <= p0+31 <= 2047 always
          bool fullv = (cb >= 0) && (cb + 3 <= ih) && (cb + 3 < WDIM);
          if (fullv) {
            v = *(const float4*)(xp + (size_t)ih * WDIM + cb);
          } else {
            float* vv = &v.x;
#pragma unroll
            for (int e = 0; e < 4; ++e) {
              int iw = cb + e;
              if (iw >= 0 && iw < WDIM && iw <= ih)
                vv[e] = xp[(size_t)ih * WDIM + iw];
            }
          }
        }
        *(float4*)(buf + slot * 4) = v;
      }
    }
  }
}

static __device__ __forceinline__ void compute_tile(
    const float* __restrict__ lb, float* __restrict__ op, const f16x8* aw,
    int p0, int q0, int tid) {
  const int lane = tid & 63;
  const int j16 = lane & 15;   // B: n (local p) / D: col
  const int wk  = lane >> 4;   // k-octet / D row quartet
  const int wid = tid >> 6;
  const int h  = wid & 1;      // p-half of sub-tile (16 rows)
  const int qh = wid >> 1;     // q-half (32 cols)

  f32x4 acc[2];
  acc[0] = (f32x4){0.f, 0.f, 0.f, 0.f};
  acc[1] = (f32x4){0.f, 0.f, 0.f, 0.f};

#pragma unroll
  for (int qt = 0; qt < 2; ++qt) {
#pragma unroll
    for (int r = 0; r < 6; ++r) {
      // B[k=8wk+i, n=j16] = x_tile[16h + j16 + r, 32qh + 16qt + 8wk + i]
      int off = (16 * h + j16 + r) * PITCHF + 32 * qh + 16 * qt + 8 * wk;
      f32x4 lo = *(const f32x4*)&lb[off];
      f32x4 hi = *(const f32x4*)&lb[off + 4];
      acc[qt] = __builtin_amdgcn_mfma_f32_16x16x32_f16(aw[r], pack8(lo, hi),
                                                       acc[qt], 0, 0, 0);
    }
  }

  // D: col = n = j16 (p-axis), row = m = 4wk+reg (q-axis) -> float4 q-stores.
  const int p = p0 + 16 * h + j16;
  const bool needmask = (q0 + 63 > p0);
#pragma unroll
  for (int qt = 0; qt < 2; ++qt) {
    const int q = q0 + 32 * qh + 16 * qt + 4 * wk;
    f32x4 a = acc[qt];
    if (needmask) {
#pragma unroll
      for (int reg = 0; reg < 4; ++reg)
        if (q + reg > p) a[reg] = 0.f;
    }
    *(float4*)(op + (size_t)p * WDIM + q) = make_float4(a[0], a[1], a[2], a[3]);
  }
}

__global__ __launch_bounds__(256, 6)
void dwconv_mfma(const float* __restrict__ x, const float* __restrict__ wgt,
                 float* __restrict__ out) {
  const int bx = blockIdx.x, by = blockIdx.y, plane = blockIdx.z;
  const int q0 = bx * 64, p0 = by * 64;
  const int tid = threadIdx.x;
  const size_t pb = (size_t)plane * HDIM * WDIM;
  const float* __restrict__ xp = x + pb;
  float* __restrict__ op = out + pb;

  // ---- Strictly-upper block: zeros only ----
  if (by < bx) {
    const float4 z = make_float4(0.f, 0.f, 0.f, 0.f);
#pragma unroll
    for (int i = 0; i < 4; ++i) {  // 64 rows x 16 float4
      int idx = i * 256 + tid;
      int row = idx >> 4, c4 = idx & 15;
      *(float4*)(op + (size_t)(p0 + row) * WDIM + q0 + 4 * c4) = z;
    }
    return;
  }

  __shared__ __attribute__((aligned(16))) float sx[2][TROWS * PITCHF];  // 23.7KB

  // ---- Toeplitz A-fragments: lane holds A[m=j16, k=8wk+i] = w[r, k-m-3] ----
  const int lane = tid & 63;
  const int j16 = lane & 15;
  const int wk = lane >> 4;
  const float* __restrict__ wcp = wgt + (plane & (CH - 1)) * 66;
  f16x8 aw[6];
#pragma unroll
  for (int r = 0; r < 6; ++r) {
#pragma unroll
    for (int i = 0; i < 8; ++i) {
      int d = 8 * wk + i - j16 - 3;  // tap index s
      aw[r][i] = (_Float16)((d >= 0 && d <= 10) ? wcp[r * 11 + d] : 0.f);
    }
  }

  // ---- two-sub-tile pipeline, zero register carry across phases ----
  stage_tile(xp, p0, q0, bx, tid, sx[0]);
  __syncthreads();                       // drain A
  stage_tile(xp, p0 + 32, q0, bx, tid, sx[1]);  // async DMA rides under A
  compute_tile(sx[0], op, aw, p0, q0, tid);
  __syncthreads();                       // drain B
  compute_tile(sx[1], op, aw, p0 + 32, q0, tid);
}

extern "C" void kernel_launch(void* const* d_in, const int* in_sizes, int n_in,
                              void* d_out, int out_size, void* d_ws, size_t ws_size,
                              hipStream_t stream) {
  const float* x   = (const float*)d_in[0];
  const float* wgt = (const float*)d_in[1];
  float* out       = (float*)d_out;
  dim3 grid(WDIM / 64, HDIM / 64, 2 * CH);  // (32, 32, 32)
  dwconv_mfma<<<grid, dim3(256), 0, stream>>>(x, wgt, out);
}

// Round 14
// 334.348 us; speedup vs baseline: 1.4172x; 1.4172x over previous
//
#include <hip/hip_runtime.h>
#include <stdint.h>

// Depthwise causal conv via MFMA Toeplitz, f16, one-shot 64x64 blocks,
// TWO batch planes fused per block (planes zp and zp+16 share channel zp ->
// identical weights, identical causal geometry).
//   y[p,q] = sum_{r,s} w[r,s] * xm[p+r-5, q+s-5], xm/out causally masked.
// A = Toeplitz weights (m = local q), B = x tile (n = local p):
//   A[m,k] = w[r, k-m-3] for k-m-3 in [0,10] else 0
//   B[k,n] = x[p0 + n + r - 5, q0 - 8 + 16*qt + k]
// One-shot: stage plane0 + plane1 (f16 to LDS) | weight build | sync |
// compute+store plane0 | compute+store plane1.  No register carry of staged
// data across phases (r3/r7/r10 spill law); aw[6] carry proven clean (r13).
// N=2, C=16, H=W=2048.

#define HDIM 2048
#define WDIM 2048
#define CH   16

#define PITCH 80            // f16 per LDS row (160B)
#define XROWS 69            // 64 + 5 halo rows
#define NSL   (XROWS * 20)  // 16B-granule slots per plane: 1380

typedef float    f32x4 __attribute__((ext_vector_type(4)));
typedef __fp16   h16x2 __attribute__((ext_vector_type(2)));
typedef _Float16 f16x8 __attribute__((ext_vector_type(8)));

__global__ __launch_bounds__(256, 6)
void dwconv_mfma(const float* __restrict__ x, const float* __restrict__ wgt,
                 float* __restrict__ out) {
  const int bx = blockIdx.x, by = blockIdx.y, zp = blockIdx.z;
  const int q0 = bx * 64, p0 = by * 64;
  const int tid = threadIdx.x;
  const size_t pb0 = (size_t)zp * HDIM * WDIM;
  const size_t pb1 = (size_t)(zp + CH) * HDIM * WDIM;

  // ---- Strictly-upper block: zeros for both planes ----
  if (by < bx) {
    const float4 z = make_float4(0.f, 0.f, 0.f, 0.f);
    float* o0 = out + pb0 + (size_t)p0 * WDIM + q0;
    float* o1 = out + pb1 + (size_t)p0 * WDIM + q0;
#pragma unroll
    for (int i = 0; i < 4; ++i) {  // 64 rows x 16 float4 per plane
      int idx = i * 256 + tid;
      int row = idx >> 4, c4 = idx & 15;
      *(float4*)(o0 + (size_t)row * WDIM + 4 * c4) = z;
      *(float4*)(o1 + (size_t)row * WDIM + 4 * c4) = z;
    }
    return;
  }

  __shared__ __attribute__((aligned(16))) _Float16 sx[2][XROWS * PITCH]; // 22.1KB

  // pure: staged rows [p0-5,p0+63], cols [q0-8,q0+71] in-bounds AND causal.
  const bool pure = (bx >= 1) && (bx <= 30) && (by >= bx + 2);

  // ---- Stage one plane as f16 (load -> cvt_pkrtz -> ds_write, transient) ----
  auto stage_plane = [&](const float* __restrict__ xpl,
                         _Float16* __restrict__ buf) {
#pragma unroll
    for (int j = 0; j < 6; ++j) {
      int slot = j * 256 + tid;
      if (slot < NSL) {
        int row = slot / 20;
        int c4 = slot - row * 20;
        int ih = p0 - 5 + row;
        int cb = q0 - 8 + 4 * c4;
        float4 v = make_float4(0.f, 0.f, 0.f, 0.f);
        if (pure) {
          v = *(const float4*)(xpl + (size_t)ih * WDIM + cb);
        } else if (ih >= 0) {  // ih <= p0+63 <= 2047 always
          bool fullv = (cb >= 0) && (cb + 3 <= ih) && (cb + 3 < WDIM);
          if (fullv) {
            v = *(const float4*)(xpl + (size_t)ih * WDIM + cb);
          } else {
            float* vv = &v.x;
#pragma unroll
            for (int e = 0; e < 4; ++e) {
              int iw = cb + e;
              if (iw >= 0 && iw < WDIM && iw <= ih)
                vv[e] = xpl[(size_t)ih * WDIM + iw];
            }
          }
        }
        union { h16x2 h[2]; uint2 u; } cv;
        cv.h[0] = __builtin_amdgcn_cvt_pkrtz(v.x, v.y);
        cv.h[1] = __builtin_amdgcn_cvt_pkrtz(v.z, v.w);
        *(uint2*)&buf[row * PITCH + 4 * c4] = cv.u;
      }
    }
  };

  stage_plane(x + pb0, &sx[0][0]);
  stage_plane(x + pb1, &sx[1][0]);

  // ---- Toeplitz A-fragments: lane holds A[m=j16, k=8wk+i] = w[r, k-m-3] ----
  const int lane = tid & 63;
  const int j16 = lane & 15;   // A: m / B: n / D: col
  const int wk  = lane >> 4;   // k-octet / D row quartet
  const int wid = tid >> 6;    // wave -> 16-row p-strip
  const float* __restrict__ wcp = wgt + zp * 66;
  f16x8 aw[6];
#pragma unroll
  for (int r = 0; r < 6; ++r) {
#pragma unroll
    for (int i = 0; i < 8; ++i) {
      int d = 8 * wk + i - j16 - 3;  // tap index s
      aw[r][i] = (_Float16)((d >= 0 && d <= 10) ? wcp[r * 11 + d] : 0.f);
    }
  }

  __syncthreads();

  const bool dmask = (by == bx);  // only diagonal blocks cross p==q

  // ---- Compute + store, one plane at a time (acc reused, aw shared) ----
#pragma unroll 1
  for (int pl = 0; pl < 2; ++pl) {
    const _Float16* __restrict__ lb = &sx[pl][0];
    float* __restrict__ op = out + (pl ? pb1 : pb0);

    f32x4 acc[4];
#pragma unroll
    for (int qt = 0; qt < 4; ++qt) acc[qt] = (f32x4){0.f, 0.f, 0.f, 0.f};

#pragma unroll
    for (int qt = 0; qt < 4; ++qt) {
#pragma unroll
      for (int r = 0; r < 6; ++r) {
        // B[k=8wk+i, n=j16] = x_tile[16*wid + j16 + r, 16qt + 8wk + i]
        int off = (16 * wid + j16 + r) * PITCH + 16 * qt + 8 * wk;
        f16x8 xb = *(const f16x8*)&lb[off];
        acc[qt] =
            __builtin_amdgcn_mfma_f32_16x16x32_f16(aw[r], xb, acc[qt], 0, 0, 0);
      }
    }

    // D: col = n = j16 (p-axis), row = m = 4wk+reg (q-axis) -> float4 stores.
    const int p = p0 + 16 * wid + j16;
#pragma unroll
    for (int qt = 0; qt < 4; ++qt) {
      const int q = q0 + 16 * qt + 4 * wk;
      f32x4 a = acc[qt];
      if (dmask) {
#pragma unroll
        for (int reg = 0; reg < 4; ++reg)
          if (q + reg > p) a[reg] = 0.f;
      }
      *(float4*)(op + (size_t)p * WDIM + q) =
          make_float4(a[0], a[1], a[2], a[3]);
    }
  }
}

extern "C" void kernel_launch(void* const* d_in, const int* in_sizes, int n_in,
                              void* d_out, int out_size, void* d_ws, size_t ws_size,
                              hipStream_t stream) {
  const float* x   = (const float*)d_in[0];
  const float* wgt = (const float*)d_in[1];
  float* out       = (float*)d_out;
  dim3 grid(WDIM / 64, HDIM / 64, CH);  // (32, 32, 16): z = channel (2 planes)
  dwconv_mfma<<<grid, dim3(256), 0, stream>>>(x, wgt, out);
}